// Round 5
// baseline (1016.977 us; speedup 1.0000x reference)
//
#include <hip/hip_runtime.h>
#include <stdint.h>
#include <stddef.h>

#define GG 256  // voxel grid extent per axis
#define STP 16  // stats padding stride (floats) - one 64B line per counter

typedef __attribute__((ext_vector_type(8))) short bf16x8;
typedef __attribute__((ext_vector_type(4))) float f32x4;

__device__ __forceinline__ float bf2f(short s) {
  return __builtin_bit_cast(float, ((unsigned)(unsigned short)s) << 16);
}
__device__ __forceinline__ short f2bf(float f) {
  unsigned u = __builtin_bit_cast(unsigned, f);
  unsigned r = (u + 0x7FFFu + ((u >> 16) & 1u)) >> 16;
  return (short)r;
}

// ---------------- rulebook construction ----------------

__global__ __launch_bounds__(256) void k_clear_grid(uint32_t* g, int n32) {
  int i = blockIdx.x * 256 + threadIdx.x;
  int stride = gridDim.x * 256;
  for (; i < n32; i += stride) g[i] = 0xFFFFFFFFu;
}

__global__ __launch_bounds__(256) void k_scatter(const int* __restrict__ coords,
                                                 uint16_t* __restrict__ grid, int n) {
  int i = blockIdx.x * 256 + threadIdx.x;
  if (i >= n) return;
  int x = coords[3 * i], y = coords[3 * i + 1], z = coords[3 * i + 2];
  grid[(((x << 8) | y) << 8) | z] = (uint16_t)i;
}

__global__ __launch_bounds__(256) void k_rulebook(const int* __restrict__ coords,
                                                  const uint16_t* __restrict__ grid,
                                                  short* __restrict__ nidx, int n) {
  int i = blockIdx.x * 256 + threadIdx.x;
  if (i >= n) return;
  int x = coords[3 * i], y = coords[3 * i + 1], z = coords[3 * i + 2];
  int k = 0;
  for (int dx = -1; dx <= 1; ++dx)
    for (int dy = -1; dy <= 1; ++dy)
      for (int dz = -1; dz <= 1; ++dz) {
        int nx = x + dx, ny = y + dy, nz = z + dz;
        short v = -1;
        if (((nx | ny | nz) >= 0) && nx < GG && ny < GG && nz < GG) {
          uint16_t s = grid[(((nx << 8) | ny) << 8) | nz];
          if (s != 0xFFFFu) v = (short)s;  // n < 32768 so id fits
        }
        nidx[k * n + i] = v;
        ++k;
      }
}

// ---------------- misc zero (stats + zero-page) ----------------

__global__ __launch_bounds__(256) void k_zero(float* __restrict__ stats, float* __restrict__ zp) {
  int tot = 13 * 256 * STP;
  for (int i = blockIdx.x * 256 + threadIdx.x; i < tot; i += gridDim.x * 256) stats[i] = 0.0f;
  if (blockIdx.x == 0 && threadIdx.x < 64) zp[threadIdx.x] = 0.0f;
}

// ---------------- weight pack: W[27][ci][co] f32 -> P[kb][co][32] bf16 ----------------

struct PackArgs {
  const float* W[13];
  short* P[13];
  int ci[13], co[13], nkb[13];
};

__global__ __launch_bounds__(256) void k_pack(PackArgs pa) {
  int L = blockIdx.y;
  int ci = pa.ci[L], co = pa.co[L], nkb = pa.nkb[L];
  int total = nkb * co * 32;
  const float* W = pa.W[L];
  short* P = pa.P[L];
  for (int e = blockIdx.x * 256 + threadIdx.x; e < total; e += gridDim.x * 256) {
    int kk = e & 31;
    int rest = e >> 5;
    int c = rest % co;
    int kb = rest / co;
    int k = kb * 32 + kk;
    int tap = k / ci, cc = k % ci;
    float v = (tap < 27) ? W[((size_t)tap * ci + cc) * co + c] : 0.0f;
    P[e] = f2bf(v);
  }
}

// ---------------- layer 0 (Ci=4 -> Co=16), f32 VALU ----------------

__global__ __launch_bounds__(256) void k_sconv_l0(const float* __restrict__ feat,
                                                  const float* __restrict__ W,  // [27][4][16]
                                                  const short* __restrict__ nidx,
                                                  float* __restrict__ y,
                                                  float* __restrict__ stats, int n) {
  int i = blockIdx.x * 256 + threadIdx.x;
  bool act = i < n;
  int ii = act ? i : (n - 1);
  float acc[16];
#pragma unroll
  for (int c = 0; c < 16; ++c) acc[c] = 0.0f;
  for (int t = 0; t < 27; ++t) {
    int nid = nidx[t * n + ii];
    float4 f = make_float4(0.f, 0.f, 0.f, 0.f);
    if (act && nid >= 0) f = *(const float4*)(feat + 4 * (size_t)nid);
    const float* Wt = W + t * 64;
#pragma unroll
    for (int c = 0; c < 16; ++c)
      acc[c] = fmaf(f.x, Wt[c],
               fmaf(f.y, Wt[16 + c],
               fmaf(f.z, Wt[32 + c],
               fmaf(f.w, Wt[48 + c], acc[c]))));
  }
  if (act) {
    float* o = y + (size_t)i * 16;
#pragma unroll
    for (int c = 0; c < 16; c += 4) *(float4*)(o + c) = make_float4(acc[c], acc[c+1], acc[c+2], acc[c+3]);
  }
  __shared__ float ss[4][16], sq[4][16];
  int w = threadIdx.x >> 6, l = threadIdx.x & 63;
#pragma unroll
  for (int c = 0; c < 16; ++c) {
    float s = act ? acc[c] : 0.0f;
    float q = s * s;
#pragma unroll
    for (int off = 32; off; off >>= 1) {
      s += __shfl_xor(s, off);
      q += __shfl_xor(q, off);
    }
    if (l == 0) { ss[w][c] = s; sq[w][c] = q; }
  }
  __syncthreads();
  if (threadIdx.x < 16) {
    int c = threadIdx.x;
    atomicAdd(&stats[c * STP], ss[0][c] + ss[1][c] + ss[2][c] + ss[3][c]);
    atomicAdd(&stats[(16 + c) * STP], sq[0][c] + sq[1][c] + sq[2][c] + sq[3][c]);
  }
}

// ---------------- MFMA sparse conv ----------------
// Wave-per-(m,n)-tile. Block = 256 thr = 4 waves covering MT m-tiles (16 rows
// each) x WPM n-tile-owners. nidx staged in LDS once. Depth-2 prefetch of A/B.
// A gathered per-lane from global (L2); invalid -> zero page (branch-free).
// BN partials indexed by [mt][col]: exactly one wave writes each entry
// (wave = mt*WPM + col/16 for j=0; NT=2 slices are also unique) -- no
// uninitialized-LDS reads (R4 bug).

template <int CI, int CO>
__global__ __launch_bounds__(256) void k_sconv_mfma(
    const short* __restrict__ feat, const short* __restrict__ P,
    const short* __restrict__ nidx, const short* __restrict__ zpage,
    float* __restrict__ y, float* __restrict__ stats, int n) {
  constexpr int LOG2CI = (CI == 16) ? 4 : (CI == 32) ? 5 : 6;
  constexpr int NKB = (27 * CI + 31) / 32;        // K-steps of 32
  constexpr int MT = (CO == 16) ? 4 : (CO == 32) ? 2 : 1;  // m-tiles per block
  constexpr int WPM = 4 / MT;                     // waves per m-tile
  constexpr int NT = (CO == 128) ? 2 : 1;         // n-tiles per wave
  constexpr int R = MT * 16;                      // rows per block

  const int w = threadIdx.x >> 6;
  const int l = threadIdx.x & 63;
  const int lo = l & 15, g = l >> 4;
  const int mt = w / WPM;
  const int nw = w % WPM;
  const int bvox = blockIdx.x * R;

  __shared__ short nid_s[27][R];
  for (int idx = threadIdx.x; idx < 27 * R; idx += 256) {
    int tap = idx / R, r = idx % R;
    int v = bvox + r;
    nid_s[tap][r] = (v < n) ? nidx[tap * n + v] : (short)-1;
  }
  __syncthreads();

  const int rowl = mt * 16 + lo;  // this lane's A-row within block

  auto loadA = [&](int kb) -> bf16x8 {
    int kg = kb * 32 + 8 * g;
    int tap = kg >> LOG2CI;
    int ch = kg & (CI - 1);
    const short* ap = zpage;
    if (tap < 27) {
      int nid = nid_s[tap][rowl];
      if (nid >= 0) ap = feat + (size_t)nid * CI + ch;
    }
    return *(const bf16x8*)ap;
  };
  auto loadB = [&](int kb, int j) -> bf16x8 {
    int t = nw + j * WPM;
    return *(const bf16x8*)(P + ((size_t)(kb * CO + 16 * t + lo)) * 32 + 8 * g);
  };

  f32x4 acc[NT];
#pragma unroll
  for (int j = 0; j < NT; ++j) acc[j] = (f32x4){0.f, 0.f, 0.f, 0.f};

  bf16x8 aC = loadA(0), aN = loadA(1);
  bf16x8 bC[NT], bN[NT];
#pragma unroll
  for (int j = 0; j < NT; ++j) { bC[j] = loadB(0, j); bN[j] = loadB(1, j); }

#pragma unroll 2
  for (int kb = 0; kb < NKB; ++kb) {
    bf16x8 aP = aC;  // defined value; overwritten when in range
    bf16x8 bP[NT];
#pragma unroll
    for (int j = 0; j < NT; ++j) bP[j] = bC[j];
    if (kb + 2 < NKB) {
      aP = loadA(kb + 2);
#pragma unroll
      for (int j = 0; j < NT; ++j) bP[j] = loadB(kb + 2, j);
    }
#pragma unroll
    for (int j = 0; j < NT; ++j)
      acc[j] = __builtin_amdgcn_mfma_f32_16x16x32_bf16(aC, bC[j], acc[j], 0, 0, 0);
    aC = aN; aN = aP;
#pragma unroll
    for (int j = 0; j < NT; ++j) { bC[j] = bN[j]; bN[j] = bP[j]; }
  }

  // epilogue: write y (f32) + fused BN partial sums, indexed [mt][col]
  __shared__ float ss[MT][CO], sq[MT][CO];
#pragma unroll
  for (int j = 0; j < NT; ++j) {
    int col = 16 * (nw + j * WPM) + lo;
    float sv = 0.f, qv = 0.f;
#pragma unroll
    for (int r = 0; r < 4; ++r) {
      int row = bvox + mt * 16 + 4 * g + r;
      float v = acc[j][r];
      bool valid = row < n;
      if (valid) y[(size_t)row * CO + col] = v;
      v = valid ? v : 0.f;
      sv += v;
      qv += v * v;
    }
    sv += __shfl_xor(sv, 16); sv += __shfl_xor(sv, 32);
    qv += __shfl_xor(qv, 16); qv += __shfl_xor(qv, 32);
    if (g == 0) { ss[mt][col] = sv; sq[mt][col] = qv; }
  }
  __syncthreads();
  for (int c = threadIdx.x; c < CO; c += 256) {
    float s = 0.f, q = 0.f;
#pragma unroll
    for (int m = 0; m < MT; ++m) { s += ss[m][c]; q += sq[m][c]; }
    atomicAdd(&stats[c * STP], s);
    atomicAdd(&stats[(CO + c) * STP], q);
  }
}

// ---------------- BN apply + ReLU (+dtype conversion) ----------------

template <int CO, bool OUTF32>
__global__ __launch_bounds__(256) void k_bn_apply(const float* __restrict__ yv,
                                                  const float* __restrict__ stats,
                                                  const float* __restrict__ gam,
                                                  const float* __restrict__ bet,
                                                  void* __restrict__ outv, int n) {
  int idx = blockIdx.x * 256 + threadIdx.x;
  int tot = n * CO / 8;
  if (idx >= tot) return;
  size_t e0 = (size_t)idx * 8;
  int c0 = (int)(e0 & (CO - 1));
  float invn = 1.0f / (float)n;

  const float4* p = (const float4*)(yv + e0);
  float4 u0 = p[0], u1 = p[1];
  float vin[8] = {u0.x, u0.y, u0.z, u0.w, u1.x, u1.y, u1.z, u1.w};

  float vout[8];
#pragma unroll
  for (int j = 0; j < 8; ++j) {
    int c = c0 + j;
    float m = stats[c * STP] * invn;
    float var = fmaf(-m, m, stats[(CO + c) * STP] * invn);
    float rstd = rsqrtf(var + 1e-3f);
    float o = fmaf((vin[j] - m) * rstd, gam[c], bet[c]);
    vout[j] = fmaxf(o, 0.0f);
  }

  if (OUTF32) {
    float4* q = (float4*)((float*)outv + e0);
    q[0] = make_float4(vout[0], vout[1], vout[2], vout[3]);
    q[1] = make_float4(vout[4], vout[5], vout[6], vout[7]);
  } else {
    bf16x8 o;
#pragma unroll
    for (int j = 0; j < 8; ++j) o[j] = f2bf(vout[j]);
    *(bf16x8*)((short*)outv + e0) = o;
  }
}

// ---------------- host ----------------

extern "C" void kernel_launch(void* const* d_in, const int* in_sizes, int n_in,
                              void* d_out, int out_size, void* d_ws, size_t ws_size,
                              hipStream_t stream) {
  const float* vf = (const float*)d_in[0];
  const int* coords = (const int*)d_in[1];
  const int n = in_sizes[1] / 3;

  static const int CIs[13] = {4, 16, 16, 32, 32, 32, 64, 64, 64, 64, 64, 64, 64};
  static const int COs[13] = {16, 16, 32, 32, 32, 64, 64, 64, 64, 64, 64, 64, 128};

  char* ws = (char*)d_ws;
  size_t off = 0;
  auto carve = [&](size_t bytes) { void* p = ws + off; off = (off + bytes + 255) & ~(size_t)255; return p; };
  uint16_t* grid = (uint16_t*)carve((size_t)GG * GG * GG * 2);   // 33.55 MB
  short* nidx = (short*)carve((size_t)27 * n * 2);               // 1.62 MB
  short* featA = (short*)carve((size_t)n * 128 * 2);             // 7.68 MB
  short* featB = (short*)carve((size_t)n * 128 * 2);             // 7.68 MB
  float* y = (float*)carve((size_t)n * 128 * 4);                 // 15.36 MB
  short* Ppool = (short*)carve((size_t)4 * 1024 * 1024);         // 4 MB
  float* stats = (float*)carve((size_t)13 * 256 * STP * 4);      // 208 KB
  float* zpage = (float*)carve(256);

  PackArgs pa;
  {
    size_t poff = 0;
    for (int L = 0; L < 13; ++L) {
      int ci = CIs[L], co = COs[L];
      int nkb = (27 * ci + 31) / 32;
      pa.W[L] = (const float*)d_in[2 + 3 * L];
      pa.P[L] = Ppool + poff;
      pa.ci[L] = ci; pa.co[L] = co; pa.nkb[L] = nkb;
      poff += (size_t)nkb * co * 32;
    }
  }

  const int n32 = GG * GG * GG / 2;
  k_clear_grid<<<2048, 256, 0, stream>>>((uint32_t*)grid, n32);
  k_scatter<<<(n + 255) / 256, 256, 0, stream>>>(coords, grid, n);
  k_rulebook<<<(n + 255) / 256, 256, 0, stream>>>(coords, grid, nidx, n);
  k_zero<<<208, 256, 0, stream>>>(stats, zpage);
  k_pack<<<dim3(128, 13), 256, 0, stream>>>(pa);

  // ---- layer 0 (f32 path) ----
  k_sconv_l0<<<(n + 255) / 256, 256, 0, stream>>>(vf, pa.W[0], nidx, y, stats, n);
  k_bn_apply<16, false><<<((n * 16 / 8) + 255) / 256, 256, 0, stream>>>(
      y, stats, (const float*)d_in[3], (const float*)d_in[4], (void*)featA, n);

  // ---- layers 1..12 (MFMA path) ----
  short* cur = featA;
  short* nxt = featB;

#define RUN_MFMA(L, CI, CO, LAST)                                                             \
  do {                                                                                        \
    constexpr int MT_ = ((CO) == 16) ? 4 : ((CO) == 32) ? 2 : 1;                              \
    const int nblk = (n + MT_ * 16 - 1) / (MT_ * 16);                                         \
    float* st = stats + 256 * STP * (L);                                                      \
    k_sconv_mfma<CI, CO><<<nblk, 256, 0, stream>>>(cur, (const short*)pa.P[L], nidx,          \
                                                   (const short*)zpage, y, st, n);            \
    const float* gg = (const float*)d_in[3 + 3 * (L)];                                        \
    const float* bb = (const float*)d_in[4 + 3 * (L)];                                        \
    int nb = ((n * (CO) / 8) + 255) / 256;                                                    \
    if (LAST) {                                                                               \
      k_bn_apply<CO, true><<<nb, 256, 0, stream>>>(y, st, gg, bb, (void*)d_out, n);           \
    } else {                                                                                  \
      k_bn_apply<CO, false><<<nb, 256, 0, stream>>>(y, st, gg, bb, (void*)nxt, n);            \
      short* t_ = cur; cur = nxt; nxt = t_;                                                   \
    }                                                                                         \
  } while (0)

  RUN_MFMA(1, 16, 16, false);
  RUN_MFMA(2, 16, 32, false);
  RUN_MFMA(3, 32, 32, false);
  RUN_MFMA(4, 32, 32, false);
  RUN_MFMA(5, 32, 64, false);
  RUN_MFMA(6, 64, 64, false);
  RUN_MFMA(7, 64, 64, false);
  RUN_MFMA(8, 64, 64, false);
  RUN_MFMA(9, 64, 64, false);
  RUN_MFMA(10, 64, 64, false);
  RUN_MFMA(11, 64, 64, false);
  RUN_MFMA(12, 64, 128, true);
#undef RUN_MFMA
}

// Round 6
// 794.654 us; speedup vs baseline: 1.2798x; 1.2798x over previous
//
#include <hip/hip_runtime.h>
#include <stdint.h>
#include <stddef.h>

#define GG 256  // voxel grid extent per axis
#define STP 16  // stats padding stride (floats) - one 64B line per counter

typedef __attribute__((ext_vector_type(8))) short bf16x8;
typedef __attribute__((ext_vector_type(4))) float f32x4;

__device__ __forceinline__ float bf2f(short s) {
  return __builtin_bit_cast(float, ((unsigned)(unsigned short)s) << 16);
}
__device__ __forceinline__ short f2bf(float f) {
  unsigned u = __builtin_bit_cast(unsigned, f);
  unsigned r = (u + 0x7FFFu + ((u >> 16) & 1u)) >> 16;
  return (short)r;
}

// ---------------- rulebook construction ----------------

__global__ __launch_bounds__(256) void k_clear_grid(uint32_t* g, int n32) {
  int i = blockIdx.x * 256 + threadIdx.x;
  int stride = gridDim.x * 256;
  for (; i < n32; i += stride) g[i] = 0xFFFFFFFFu;
}

__global__ __launch_bounds__(256) void k_scatter(const int* __restrict__ coords,
                                                 uint16_t* __restrict__ grid, int n) {
  int i = blockIdx.x * 256 + threadIdx.x;
  if (i >= n) return;
  int x = coords[3 * i], y = coords[3 * i + 1], z = coords[3 * i + 2];
  grid[(((x << 8) | y) << 8) | z] = (uint16_t)i;
}

__global__ __launch_bounds__(256) void k_rulebook(const int* __restrict__ coords,
                                                  const uint16_t* __restrict__ grid,
                                                  short* __restrict__ nidx, int n) {
  int i = blockIdx.x * 256 + threadIdx.x;
  if (i >= n) return;
  int x = coords[3 * i], y = coords[3 * i + 1], z = coords[3 * i + 2];
  int k = 0;
  for (int dx = -1; dx <= 1; ++dx)
    for (int dy = -1; dy <= 1; ++dy)
      for (int dz = -1; dz <= 1; ++dz) {
        int nx = x + dx, ny = y + dy, nz = z + dz;
        short v = -1;
        if (((nx | ny | nz) >= 0) && nx < GG && ny < GG && nz < GG) {
          uint16_t s = grid[(((nx << 8) | ny) << 8) | nz];
          if (s != 0xFFFFu) v = (short)s;  // n < 32768 so id fits
        }
        nidx[k * n + i] = v;
        ++k;
      }
}

// ---------------- misc zero (stats + zero-page) ----------------

__global__ __launch_bounds__(256) void k_zero(float* __restrict__ stats, float* __restrict__ zp) {
  int tot = 13 * 256 * STP;
  for (int i = blockIdx.x * 256 + threadIdx.x; i < tot; i += gridDim.x * 256) stats[i] = 0.0f;
  if (blockIdx.x == 0 && threadIdx.x < 64) zp[threadIdx.x] = 0.0f;
}

// ---------------- weight pack: W[27][ci][co] f32 -> P[kb][co][32] bf16 ----------------

struct PackArgs {
  const float* W[13];
  short* P[13];
  int ci[13], co[13], nkb[13];
};

__global__ __launch_bounds__(256) void k_pack(PackArgs pa) {
  int L = blockIdx.y;
  int ci = pa.ci[L], co = pa.co[L], nkb = pa.nkb[L];
  int total = nkb * co * 32;
  const float* W = pa.W[L];
  short* P = pa.P[L];
  for (int e = blockIdx.x * 256 + threadIdx.x; e < total; e += gridDim.x * 256) {
    int kk = e & 31;
    int rest = e >> 5;
    int c = rest % co;
    int kb = rest / co;
    int k = kb * 32 + kk;
    int tap = k / ci, cc = k % ci;
    float v = (tap < 27) ? W[((size_t)tap * ci + cc) * co + c] : 0.0f;
    P[e] = f2bf(v);
  }
}

// ---------------- layer 0 (Ci=4 -> Co=16), f32 VALU ----------------

__global__ __launch_bounds__(256) void k_sconv_l0(const float* __restrict__ feat,
                                                  const float* __restrict__ W,  // [27][4][16]
                                                  const short* __restrict__ nidx,
                                                  float* __restrict__ y,
                                                  float* __restrict__ stats, int n) {
  int i = blockIdx.x * 256 + threadIdx.x;
  bool act = i < n;
  int ii = act ? i : (n - 1);
  float acc[16];
#pragma unroll
  for (int c = 0; c < 16; ++c) acc[c] = 0.0f;
  for (int t = 0; t < 27; ++t) {
    int nid = nidx[t * n + ii];
    float4 f = make_float4(0.f, 0.f, 0.f, 0.f);
    if (act && nid >= 0) f = *(const float4*)(feat + 4 * (size_t)nid);
    const float* Wt = W + t * 64;
#pragma unroll
    for (int c = 0; c < 16; ++c)
      acc[c] = fmaf(f.x, Wt[c],
               fmaf(f.y, Wt[16 + c],
               fmaf(f.z, Wt[32 + c],
               fmaf(f.w, Wt[48 + c], acc[c]))));
  }
  if (act) {
    float* o = y + (size_t)i * 16;
#pragma unroll
    for (int c = 0; c < 16; c += 4) *(float4*)(o + c) = make_float4(acc[c], acc[c+1], acc[c+2], acc[c+3]);
  }
  __shared__ float ss[4][16], sq[4][16];
  int w = threadIdx.x >> 6, l = threadIdx.x & 63;
#pragma unroll
  for (int c = 0; c < 16; ++c) {
    float s = act ? acc[c] : 0.0f;
    float q = s * s;
#pragma unroll
    for (int off = 32; off; off >>= 1) {
      s += __shfl_xor(s, off);
      q += __shfl_xor(q, off);
    }
    if (l == 0) { ss[w][c] = s; sq[w][c] = q; }
  }
  __syncthreads();
  if (threadIdx.x < 16) {
    int c = threadIdx.x;
    atomicAdd(&stats[c * STP], ss[0][c] + ss[1][c] + ss[2][c] + ss[3][c]);
    atomicAdd(&stats[(16 + c) * STP], sq[0][c] + sq[1][c] + sq[2][c] + sq[3][c]);
  }
}

// ---------------- MFMA sparse conv ----------------
// Per-lane register rulebook: 27 tap byte-offsets in VGPRs (static indices),
// invalid -> zoff (zeroed page, relative to feat). K-loop fully unrolled,
// depth-4 register prefetch of A and B, branch-free A addressing.
// Epilogue: acc -> LDS -> contiguous float4 store (no atomics, no stats).
// mfma_f32_16x16x32_bf16: A: lane l holds A[row=l&15][k=8*(l>>4)+b];
//                         B: lane l holds B[k=8*(l>>4)+b][col=l&15];
//                         C/D: col=l&15, row=4*(l>>4)+r.

template <int CI, int CO>
__global__ __launch_bounds__(256) void k_sconv_mfma(
    const short* __restrict__ feat, const short* __restrict__ P,
    const short* __restrict__ nidx, int zoff,
    float* __restrict__ y, int n) {
  constexpr int NKB = (27 * CI + 31) / 32;                 // K-steps of 32
  constexpr int MT = (CO == 16) ? 4 : (CO == 32) ? 2 : 1;  // m-tiles per block
  constexpr int WPM = 4 / MT;                              // waves per m-tile
  constexpr int NT = CO / (16 * WPM);                      // n-tiles per wave
  constexpr int R = MT * 16;                               // rows per block
  constexpr int PF = 4;                                    // prefetch depth

  const int w = threadIdx.x >> 6;
  const int l = threadIdx.x & 63;
  const int lo = l & 15, g = l >> 4;
  const int mt = w / WPM, nw = w % WPM;
  const int bvox = blockIdx.x * R;
  const int rowg = bvox + mt * 16 + lo;
  const int rowc = (rowg < n) ? rowg : (n - 1);

  // per-lane tap offsets (bytes into feat; zoff = zpage for invalid)
  int offs[28];
#pragma unroll
  for (int t = 0; t < 27; ++t) {
    int nid = (int)nidx[t * n + rowc];
    offs[t] = (nid >= 0) ? nid * (CI * 2) : zoff;
  }
  offs[27] = zoff;

  // per-lane A base: feat + intra-row channel byte offset
  const int chb0 = (CI == 16) ? ((g & 1) * 16) : (g * 16);
  const char* fb = (const char*)feat + chb0;

  // per-lane B base pointers (one per n-tile)
  const char* pb[NT];
#pragma unroll
  for (int j = 0; j < NT; ++j)
    pb[j] = (const char*)P + (((nw + j * WPM) * 16 + lo) * 64 + g * 16);

  auto A = [&](int kb) -> bf16x8 {
    int off;
    if (CI == 64) {
      off = offs[kb >> 1] + ((kb & 1) << 6);
    } else if (CI == 32) {
      off = offs[kb];
    } else {  // CI == 16: two taps per k-step, selected by g
      int o0 = offs[2 * kb];
      int o1 = offs[2 * kb + 1];
      off = (g < 2) ? o0 : o1;
    }
    return *(const bf16x8*)(fb + off);
  };

  bf16x8 ab[PF];
  bf16x8 bb[PF][NT];
#pragma unroll
  for (int i = 0; i < PF; ++i) {
    ab[i] = A(i);
#pragma unroll
    for (int j = 0; j < NT; ++j)
      bb[i][j] = *(const bf16x8*)(pb[j] + (size_t)i * (CO * 64));
  }

  f32x4 acc[NT];
#pragma unroll
  for (int j = 0; j < NT; ++j) acc[j] = (f32x4){0.f, 0.f, 0.f, 0.f};

#pragma unroll
  for (int kb = 0; kb < NKB; ++kb) {
    bf16x8 a = ab[kb % PF];
    bf16x8 bcur[NT];
#pragma unroll
    for (int j = 0; j < NT; ++j) bcur[j] = bb[kb % PF][j];
    if (kb + PF < NKB) {  // compile-time after unroll
      ab[kb % PF] = A(kb + PF);
#pragma unroll
      for (int j = 0; j < NT; ++j)
        bb[kb % PF][j] = *(const bf16x8*)(pb[j] + (size_t)(kb + PF) * (CO * 64));
    }
#pragma unroll
    for (int j = 0; j < NT; ++j)
      acc[j] = __builtin_amdgcn_mfma_f32_16x16x32_bf16(a, bcur[j], acc[j], 0, 0, 0);
  }

  // epilogue: stage to LDS, then contiguous coalesced float4 store
  __shared__ float ys[R * CO];
#pragma unroll
  for (int j = 0; j < NT; ++j) {
    int col = (nw + j * WPM) * 16 + lo;
#pragma unroll
    for (int r = 0; r < 4; ++r)
      ys[(mt * 16 + 4 * g + r) * CO + col] = acc[j][r];
  }
  __syncthreads();
  constexpr int IT = (R * CO / 4) / 256;  // float4s per thread
#pragma unroll
  for (int e4 = 0; e4 < IT; ++e4) {
    int e = e4 * 256 + threadIdx.x;
    int gidx = bvox * CO + e * 4;
    if (gidx < n * CO) *(float4*)(y + gidx) = *(const float4*)(ys + e * 4);
  }
}

// ---------------- BN stats over y (per-thread fixed channels, 1 flush) ----------------

template <int CO>
__global__ __launch_bounds__(256) void k_stats(const float* __restrict__ y,
                                               float* __restrict__ stats, int n) {
  const int tid = threadIdx.x;
  const int c0 = (tid * 4) & (CO - 1);  // invariant across grid-stride (stride%CO==0)
  float s0 = 0.f, s1 = 0.f, s2 = 0.f, s3 = 0.f;
  float q0 = 0.f, q1 = 0.f, q2 = 0.f, q3 = 0.f;
  const int tot4 = n * CO / 4;
  for (int i = blockIdx.x * 256 + tid; i < tot4; i += gridDim.x * 256) {
    float4 v = *(const float4*)(y + (size_t)i * 4);
    s0 += v.x; q0 += v.x * v.x;
    s1 += v.y; q1 += v.y * v.y;
    s2 += v.z; q2 += v.z * v.z;
    s3 += v.w; q3 += v.w * v.w;
  }
  __shared__ float ps[2 * CO];
  for (int i = tid; i < 2 * CO; i += 256) ps[i] = 0.f;
  __syncthreads();
  atomicAdd(&ps[c0 + 0], s0);
  atomicAdd(&ps[c0 + 1], s1);
  atomicAdd(&ps[c0 + 2], s2);
  atomicAdd(&ps[c0 + 3], s3);
  atomicAdd(&ps[CO + c0 + 0], q0);
  atomicAdd(&ps[CO + c0 + 1], q1);
  atomicAdd(&ps[CO + c0 + 2], q2);
  atomicAdd(&ps[CO + c0 + 3], q3);
  __syncthreads();
  for (int c = tid; c < CO; c += 256) {
    atomicAdd(&stats[c * STP], ps[c]);
    atomicAdd(&stats[(CO + c) * STP], ps[CO + c]);
  }
}

// ---------------- BN apply + ReLU (+dtype conversion) ----------------

template <int CO, bool OUTF32>
__global__ __launch_bounds__(256) void k_bn_apply(const float* __restrict__ yv,
                                                  const float* __restrict__ stats,
                                                  const float* __restrict__ gam,
                                                  const float* __restrict__ bet,
                                                  void* __restrict__ outv, int n) {
  int idx = blockIdx.x * 256 + threadIdx.x;
  int tot = n * CO / 8;
  if (idx >= tot) return;
  size_t e0 = (size_t)idx * 8;
  int c0 = (int)(e0 & (CO - 1));
  float invn = 1.0f / (float)n;

  const float4* p = (const float4*)(yv + e0);
  float4 u0 = p[0], u1 = p[1];
  float vin[8] = {u0.x, u0.y, u0.z, u0.w, u1.x, u1.y, u1.z, u1.w};

  float vout[8];
#pragma unroll
  for (int j = 0; j < 8; ++j) {
    int c = c0 + j;
    float m = stats[c * STP] * invn;
    float var = fmaf(-m, m, stats[(CO + c) * STP] * invn);
    float rstd = rsqrtf(var + 1e-3f);
    float o = fmaf((vin[j] - m) * rstd, gam[c], bet[c]);
    vout[j] = fmaxf(o, 0.0f);
  }

  if (OUTF32) {
    float4* q = (float4*)((float*)outv + e0);
    q[0] = make_float4(vout[0], vout[1], vout[2], vout[3]);
    q[1] = make_float4(vout[4], vout[5], vout[6], vout[7]);
  } else {
    bf16x8 o;
#pragma unroll
    for (int j = 0; j < 8; ++j) o[j] = f2bf(vout[j]);
    *(bf16x8*)((short*)outv + e0) = o;
  }
}

// ---------------- host ----------------

extern "C" void kernel_launch(void* const* d_in, const int* in_sizes, int n_in,
                              void* d_out, int out_size, void* d_ws, size_t ws_size,
                              hipStream_t stream) {
  const float* vf = (const float*)d_in[0];
  const int* coords = (const int*)d_in[1];
  const int n = in_sizes[1] / 3;

  static const int CIs[13] = {4, 16, 16, 32, 32, 32, 64, 64, 64, 64, 64, 64, 64};
  static const int COs[13] = {16, 16, 32, 32, 32, 64, 64, 64, 64, 64, 64, 64, 128};

  char* ws = (char*)d_ws;
  size_t off = 0;
  auto carve = [&](size_t bytes) { void* p = ws + off; off = (off + bytes + 255) & ~(size_t)255; return p; };
  uint16_t* grid = (uint16_t*)carve((size_t)GG * GG * GG * 2);   // 33.55 MB
  short* nidx = (short*)carve((size_t)27 * n * 2);               // 1.62 MB
  short* featA = (short*)carve((size_t)n * 128 * 2);             // 7.68 MB
  short* featB = (short*)carve((size_t)n * 128 * 2);             // 7.68 MB
  float* y = (float*)carve((size_t)n * 128 * 4);                 // 15.36 MB
  short* Ppool = (short*)carve((size_t)4 * 1024 * 1024);         // 4 MB
  float* stats = (float*)carve((size_t)13 * 256 * STP * 4);      // 208 KB
  float* zpage = (float*)carve(256);

  PackArgs pa;
  {
    size_t poff = 0;
    for (int L = 0; L < 13; ++L) {
      int ci = CIs[L], co = COs[L];
      int nkb = (27 * ci + 31) / 32;
      pa.W[L] = (const float*)d_in[2 + 3 * L];
      pa.P[L] = Ppool + poff;
      pa.ci[L] = ci; pa.co[L] = co; pa.nkb[L] = nkb;
      poff += (size_t)nkb * co * 32;
    }
  }

  const int n32 = GG * GG * GG / 2;
  k_clear_grid<<<2048, 256, 0, stream>>>((uint32_t*)grid, n32);
  k_scatter<<<(n + 255) / 256, 256, 0, stream>>>(coords, grid, n);
  k_rulebook<<<(n + 255) / 256, 256, 0, stream>>>(coords, grid, nidx, n);
  k_zero<<<208, 256, 0, stream>>>(stats, zpage);
  k_pack<<<dim3(128, 13), 256, 0, stream>>>(pa);

  // ---- layer 0 (f32 path, fused stats) ----
  k_sconv_l0<<<(n + 255) / 256, 256, 0, stream>>>(vf, pa.W[0], nidx, y, stats, n);
  k_bn_apply<16, false><<<((n * 16 / 8) + 255) / 256, 256, 0, stream>>>(
      y, stats, (const float*)d_in[3], (const float*)d_in[4], (void*)featA, n);

  // ---- layers 1..12 (MFMA path) ----
  short* cur = featA;
  short* nxt = featB;

#define RUN_MFMA(L, CI, CO, LAST)                                                             \
  do {                                                                                        \
    constexpr int MT_ = ((CO) == 16) ? 4 : ((CO) == 32) ? 2 : 1;                              \
    const int nblk = (n + MT_ * 16 - 1) / (MT_ * 16);                                         \
    float* st = stats + 256 * STP * (L);                                                      \
    int zoff = (int)((char*)zpage - (char*)cur);                                              \
    k_sconv_mfma<CI, CO><<<nblk, 256, 0, stream>>>(cur, (const short*)pa.P[L], nidx,          \
                                                   zoff, y, n);                               \
    k_stats<CO><<<256, 256, 0, stream>>>(y, st, n);                                           \
    const float* gg = (const float*)d_in[3 + 3 * (L)];                                        \
    const float* bb = (const float*)d_in[4 + 3 * (L)];                                        \
    int nb = ((n * (CO) / 8) + 255) / 256;                                                    \
    if (LAST) {                                                                               \
      k_bn_apply<CO, true><<<nb, 256, 0, stream>>>(y, st, gg, bb, (void*)d_out, n);           \
    } else {                                                                                  \
      k_bn_apply<CO, false><<<nb, 256, 0, stream>>>(y, st, gg, bb, (void*)nxt, n);            \
      short* t_ = cur; cur = nxt; nxt = t_;                                                   \
    }                                                                                         \
  } while (0)

  RUN_MFMA(1, 16, 16, false);
  RUN_MFMA(2, 16, 32, false);
  RUN_MFMA(3, 32, 32, false);
  RUN_MFMA(4, 32, 32, false);
  RUN_MFMA(5, 32, 64, false);
  RUN_MFMA(6, 64, 64, false);
  RUN_MFMA(7, 64, 64, false);
  RUN_MFMA(8, 64, 64, false);
  RUN_MFMA(9, 64, 64, false);
  RUN_MFMA(10, 64, 64, false);
  RUN_MFMA(11, 64, 64, false);
  RUN_MFMA(12, 64, 128, true);
#undef RUN_MFMA
}

// Round 10
// 724.584 us; speedup vs baseline: 1.4035x; 1.0967x over previous
//
#include <hip/hip_runtime.h>
#include <stdint.h>
#include <stddef.h>

#define GG 256  // voxel grid extent per axis
#define STP 16  // stats padding stride (floats) - one 64B line per counter

typedef __attribute__((ext_vector_type(8))) short bf16x8;
typedef __attribute__((ext_vector_type(4))) float f32x4;

__device__ __forceinline__ float bf2f(short s) {
  return __builtin_bit_cast(float, ((unsigned)(unsigned short)s) << 16);
}
__device__ __forceinline__ short f2bf(float f) {
  unsigned u = __builtin_bit_cast(unsigned, f);
  unsigned r = (u + 0x7FFFu + ((u >> 16) & 1u)) >> 16;
  return (short)r;
}

// ---------------- rulebook construction ----------------

__global__ __launch_bounds__(256) void k_clear_grid(uint32_t* g, int n32) {
  int i = blockIdx.x * 256 + threadIdx.x;
  int stride = gridDim.x * 256;
  for (; i < n32; i += stride) g[i] = 0xFFFFFFFFu;
}

__global__ __launch_bounds__(256) void k_scatter(const int* __restrict__ coords,
                                                 uint16_t* __restrict__ grid, int n) {
  int i = blockIdx.x * 256 + threadIdx.x;
  if (i >= n) return;
  int x = coords[3 * i], y = coords[3 * i + 1], z = coords[3 * i + 2];
  grid[(((x << 8) | y) << 8) | z] = (uint16_t)i;
}

__global__ __launch_bounds__(256) void k_rulebook(const int* __restrict__ coords,
                                                  const uint16_t* __restrict__ grid,
                                                  short* __restrict__ nidx, int n) {
  int i = blockIdx.x * 256 + threadIdx.x;
  if (i >= n) return;
  int x = coords[3 * i], y = coords[3 * i + 1], z = coords[3 * i + 2];
  int k = 0;
  for (int dx = -1; dx <= 1; ++dx)
    for (int dy = -1; dy <= 1; ++dy)
      for (int dz = -1; dz <= 1; ++dz) {
        int nx = x + dx, ny = y + dy, nz = z + dz;
        short v = -1;
        if (((nx | ny | nz) >= 0) && nx < GG && ny < GG && nz < GG) {
          uint16_t s = grid[(((nx << 8) | ny) << 8) | nz];
          if (s != 0xFFFFu) v = (short)s;  // n < 32768 so id fits
        }
        nidx[k * n + i] = v;
        ++k;
      }
}

// ---------------- misc zero (stats + zero-page) ----------------

__global__ __launch_bounds__(256) void k_zero(float* __restrict__ stats, float* __restrict__ zp) {
  int tot = 13 * 256 * STP;
  for (int i = blockIdx.x * 256 + threadIdx.x; i < tot; i += gridDim.x * 256) stats[i] = 0.0f;
  if (blockIdx.x == 0 && threadIdx.x < 64) zp[threadIdx.x] = 0.0f;
}

// ---------------- weight pack: W[27][ci][co] f32 -> P[kb][co][32] bf16 ----------------
// Padded to nkbp = 4*KS k-steps (zeros past tap 26) so the K-split loop is
// branch-free and uniform across waves.

struct PackArgs {
  const float* W[13];
  short* P[13];
  int ci[13], co[13], nkbp[13];
};

__global__ __launch_bounds__(256) void k_pack(PackArgs pa) {
  int L = blockIdx.y;
  int ci = pa.ci[L], co = pa.co[L], nkbp = pa.nkbp[L];
  int total = nkbp * co * 32;
  const float* W = pa.W[L];
  short* P = pa.P[L];
  for (int e = blockIdx.x * 256 + threadIdx.x; e < total; e += gridDim.x * 256) {
    int kk = e & 31;
    int rest = e >> 5;
    int c = rest % co;
    int kb = rest / co;
    int k = kb * 32 + kk;
    int tap = k / ci, cc = k % ci;
    float v = (tap < 27) ? W[((size_t)tap * ci + cc) * co + c] : 0.0f;
    P[e] = f2bf(v);
  }
}

// ---------------- layer 0 (Ci=4 -> Co=16), f32 VALU ----------------

__global__ __launch_bounds__(256) void k_sconv_l0(const float* __restrict__ feat,
                                                  const float* __restrict__ W,  // [27][4][16]
                                                  const short* __restrict__ nidx,
                                                  float* __restrict__ y,
                                                  float* __restrict__ stats, int n) {
  int i = blockIdx.x * 256 + threadIdx.x;
  bool act = i < n;
  int ii = act ? i : (n - 1);
  float acc[16];
#pragma unroll
  for (int c = 0; c < 16; ++c) acc[c] = 0.0f;
  for (int t = 0; t < 27; ++t) {
    int nid = nidx[t * n + ii];
    float4 f = make_float4(0.f, 0.f, 0.f, 0.f);
    if (act && nid >= 0) f = *(const float4*)(feat + 4 * (size_t)nid);
    const float* Wt = W + t * 64;
#pragma unroll
    for (int c = 0; c < 16; ++c)
      acc[c] = fmaf(f.x, Wt[c],
               fmaf(f.y, Wt[16 + c],
               fmaf(f.z, Wt[32 + c],
               fmaf(f.w, Wt[48 + c], acc[c]))));
  }
  if (act) {
    float* o = y + (size_t)i * 16;
#pragma unroll
    for (int c = 0; c < 16; c += 4) *(float4*)(o + c) = make_float4(acc[c], acc[c+1], acc[c+2], acc[c+3]);
  }
  __shared__ float ss[4][16], sq[4][16];
  int w = threadIdx.x >> 6, l = threadIdx.x & 63;
#pragma unroll
  for (int c = 0; c < 16; ++c) {
    float s = act ? acc[c] : 0.0f;
    float q = s * s;
#pragma unroll
    for (int off = 32; off; off >>= 1) {
      s += __shfl_xor(s, off);
      q += __shfl_xor(q, off);
    }
    if (l == 0) { ss[w][c] = s; sq[w][c] = q; }
  }
  __syncthreads();
  if (threadIdx.x < 16) {
    int c = threadIdx.x;
    atomicAdd(&stats[c * STP], ss[0][c] + ss[1][c] + ss[2][c] + ss[3][c]);
    atomicAdd(&stats[(16 + c) * STP], sq[0][c] + sq[1][c] + sq[2][c] + sq[3][c]);
  }
}

// ---------------- MFMA sparse conv, K-split across waves ----------------
// Block = 16 voxel rows; wave w owns K-steps [w*KS, (w+1)*KS) and computes
// partials for ALL CO columns (NT MFMAs per K-step -> high compute density
// per scattered A-load). No A duplication across waves; no barriers in the
// K-loop. Epilogue: 4-way partial reduction in padded LDS + coalesced store.
// TPW: taps touched per wave = wave's K-range / channels-per-tap.
//   CI=64: 2 K-steps per tap -> KS/2 (R9 bug: was KS -> waves 1..3 used
//   wrong taps). CI=32: 1 tap per K-step -> KS. CI=16: 2 taps/K-step -> 2*KS.
// mfma_f32_16x16x32_bf16: A: lane l holds A[row=l&15][k=8*(l>>4)+b];
//                         B: lane l holds B[k=8*(l>>4)+b][col=l&15];
//                         C/D: col=l&15, row=4*(l>>4)+r.

template <int CI, int CO>
__global__ __launch_bounds__(256) void k_sconv_mfma(
    const short* __restrict__ feat, const short* __restrict__ P,
    const short* __restrict__ nidx, int zoff,
    float* __restrict__ y, int n) {
  constexpr int NKB = (27 * CI + 31) / 32;  // real K-steps of 32
  constexpr int KS = (NKB + 3) / 4;         // K-steps per wave (P padded to 4*KS)
  constexpr int NT = CO / 16;               // n-tiles per wave (all columns)
  constexpr int TPW = (CI == 64) ? KS / 2 : (CI == 16) ? 2 * KS : KS;
  static_assert(CI != 64 || (KS % 2 == 0), "CI=64 path assumes even KS (half-parity from local j)");
  constexpr int PF = 2;                     // prefetch depth

  const int w = threadIdx.x >> 6;
  const int l = threadIdx.x & 63;
  const int lo = l & 15, g = l >> 4;
  const int bvox = blockIdx.x * 16;
  const int rowg = bvox + lo;
  const int rowc = (rowg < n) ? rowg : (n - 1);

  // per-lane tap offsets for this wave's K-range (bytes into feat; zoff = zpage)
  int offs[TPW];
#pragma unroll
  for (int t = 0; t < TPW; ++t) {
    int tap = TPW * w + t;
    int nid = (tap < 27) ? (int)nidx[tap * n + rowc] : -1;
    offs[t] = (nid >= 0) ? nid * (CI * 2) : zoff;
  }

  const char* fb = (const char*)feat;
  const char* pb = (const char*)P + (lo * 64 + g * 16) + (size_t)(w * KS) * (CO * 64);

  auto A = [&](int j) -> bf16x8 {  // j = local K-step, compile-time
    int off;
    if (CI == 64)      off = offs[j >> 1] + ((j & 1) << 6) + g * 16;
    else if (CI == 32) off = offs[j] + g * 16;
    else               off = offs[2 * j + (g >> 1)] + (g & 1) * 16;
    return *(const bf16x8*)(fb + off);
  };
  auto B = [&](int j, int t) -> bf16x8 {
    return *(const bf16x8*)(pb + (size_t)j * (CO * 64) + t * 1024);
  };

  f32x4 acc[NT];
#pragma unroll
  for (int t = 0; t < NT; ++t) acc[t] = (f32x4){0.f, 0.f, 0.f, 0.f};

  bf16x8 ab[PF];
  bf16x8 bb[PF][NT];
#pragma unroll
  for (int i = 0; i < PF; ++i) {
    ab[i] = A(i);
#pragma unroll
    for (int t = 0; t < NT; ++t) bb[i][t] = B(i, t);
  }

#pragma unroll
  for (int j = 0; j < KS; ++j) {
    bf16x8 a = ab[j % PF];
    bf16x8 bcur[NT];
#pragma unroll
    for (int t = 0; t < NT; ++t) bcur[t] = bb[j % PF][t];
    if (j + PF < KS) {  // compile-time after unroll
      ab[j % PF] = A(j + PF);
#pragma unroll
      for (int t = 0; t < NT; ++t) bb[j % PF][t] = B(j + PF, t);
    }
#pragma unroll
    for (int t = 0; t < NT; ++t)
      acc[t] = __builtin_amdgcn_mfma_f32_16x16x32_bf16(a, bcur[t], acc[t], 0, 0, 0);
  }

  // epilogue: 4-way cross-wave reduction via padded LDS, coalesced store
  constexpr int LDSP = CO + 4;  // keeps 16B alignment; g-groups land on
                                // banks {0,8,16,24} -> conflict-free-ish
  __shared__ float ps[4 * 16 * LDSP];
#pragma unroll
  for (int t = 0; t < NT; ++t) {
    int col = 16 * t + lo;
#pragma unroll
    for (int r = 0; r < 4; ++r)
      ps[(w * 16 + 4 * g + r) * LDSP + col] = acc[t][r];
  }
  __syncthreads();
  constexpr int NF4 = 16 * CO / 4;
#pragma unroll
  for (int e0 = 0; e0 < NF4; e0 += 256) {
    int e = e0 + threadIdx.x;
    if (NF4 % 256 != 0 && e >= NF4) break;
    int row = e / (CO / 4);
    int c4 = e % (CO / 4);
    float4 s = *(const float4*)&ps[(0 * 16 + row) * LDSP + 4 * c4];
    const float4 s1 = *(const float4*)&ps[(1 * 16 + row) * LDSP + 4 * c4];
    const float4 s2 = *(const float4*)&ps[(2 * 16 + row) * LDSP + 4 * c4];
    const float4 s3 = *(const float4*)&ps[(3 * 16 + row) * LDSP + 4 * c4];
    s.x += s1.x + s2.x + s3.x;
    s.y += s1.y + s2.y + s3.y;
    s.z += s1.z + s2.z + s3.z;
    s.w += s1.w + s2.w + s3.w;
    if (bvox + row < n) *(float4*)(y + (size_t)(bvox + row) * CO + 4 * c4) = s;
  }
}

// ---------------- BN stats over y (per-thread fixed channels, 1 flush) ----------------

template <int CO>
__global__ __launch_bounds__(256) void k_stats(const float* __restrict__ y,
                                               float* __restrict__ stats, int n) {
  const int tid = threadIdx.x;
  const int c0 = (tid * 4) & (CO - 1);  // invariant across grid-stride (stride%CO==0)
  float s0 = 0.f, s1 = 0.f, s2 = 0.f, s3 = 0.f;
  float q0 = 0.f, q1 = 0.f, q2 = 0.f, q3 = 0.f;
  const int tot4 = n * CO / 4;
  for (int i = blockIdx.x * 256 + tid; i < tot4; i += gridDim.x * 256) {
    float4 v = *(const float4*)(y + (size_t)i * 4);
    s0 += v.x; q0 += v.x * v.x;
    s1 += v.y; q1 += v.y * v.y;
    s2 += v.z; q2 += v.z * v.z;
    s3 += v.w; q3 += v.w * v.w;
  }
  __shared__ float ps[2 * CO];
  for (int i = tid; i < 2 * CO; i += 256) ps[i] = 0.f;
  __syncthreads();
  atomicAdd(&ps[c0 + 0], s0);
  atomicAdd(&ps[c0 + 1], s1);
  atomicAdd(&ps[c0 + 2], s2);
  atomicAdd(&ps[c0 + 3], s3);
  atomicAdd(&ps[CO + c0 + 0], q0);
  atomicAdd(&ps[CO + c0 + 1], q1);
  atomicAdd(&ps[CO + c0 + 2], q2);
  atomicAdd(&ps[CO + c0 + 3], q3);
  __syncthreads();
  for (int c = tid; c < CO; c += 256) {
    atomicAdd(&stats[c * STP], ps[c]);
    atomicAdd(&stats[(CO + c) * STP], ps[CO + c]);
  }
}

// ---------------- BN apply + ReLU (+dtype conversion) ----------------

template <int CO, bool OUTF32>
__global__ __launch_bounds__(256) void k_bn_apply(const float* __restrict__ yv,
                                                  const float* __restrict__ stats,
                                                  const float* __restrict__ gam,
                                                  const float* __restrict__ bet,
                                                  void* __restrict__ outv, int n) {
  int idx = blockIdx.x * 256 + threadIdx.x;
  int tot = n * CO / 8;
  if (idx >= tot) return;
  size_t e0 = (size_t)idx * 8;
  int c0 = (int)(e0 & (CO - 1));
  float invn = 1.0f / (float)n;

  const float4* p = (const float4*)(yv + e0);
  float4 u0 = p[0], u1 = p[1];
  float vin[8] = {u0.x, u0.y, u0.z, u0.w, u1.x, u1.y, u1.z, u1.w};

  float vout[8];
#pragma unroll
  for (int j = 0; j < 8; ++j) {
    int c = c0 + j;
    float m = stats[c * STP] * invn;
    float var = fmaf(-m, m, stats[(CO + c) * STP] * invn);
    float rstd = rsqrtf(var + 1e-3f);
    float o = fmaf((vin[j] - m) * rstd, gam[c], bet[c]);
    vout[j] = fmaxf(o, 0.0f);
  }

  if (OUTF32) {
    float4* q = (float4*)((float*)outv + e0);
    q[0] = make_float4(vout[0], vout[1], vout[2], vout[3]);
    q[1] = make_float4(vout[4], vout[5], vout[6], vout[7]);
  } else {
    bf16x8 o;
#pragma unroll
    for (int j = 0; j < 8; ++j) o[j] = f2bf(vout[j]);
    *(bf16x8*)((short*)outv + e0) = o;
  }
}

// ---------------- host ----------------

extern "C" void kernel_launch(void* const* d_in, const int* in_sizes, int n_in,
                              void* d_out, int out_size, void* d_ws, size_t ws_size,
                              hipStream_t stream) {
  const float* vf = (const float*)d_in[0];
  const int* coords = (const int*)d_in[1];
  const int n = in_sizes[1] / 3;

  static const int CIs[13] = {4, 16, 16, 32, 32, 32, 64, 64, 64, 64, 64, 64, 64};
  static const int COs[13] = {16, 16, 32, 32, 32, 64, 64, 64, 64, 64, 64, 64, 128};

  char* ws = (char*)d_ws;
  size_t off = 0;
  auto carve = [&](size_t bytes) { void* p = ws + off; off = (off + bytes + 255) & ~(size_t)255; return p; };
  uint16_t* grid = (uint16_t*)carve((size_t)GG * GG * GG * 2);   // 33.55 MB
  short* nidx = (short*)carve((size_t)27 * n * 2);               // 1.62 MB
  short* featA = (short*)carve((size_t)n * 128 * 2);             // 7.68 MB
  short* featB = (short*)carve((size_t)n * 128 * 2);             // 7.68 MB
  float* y = (float*)carve((size_t)n * 128 * 4);                 // 15.36 MB
  short* Ppool = (short*)carve((size_t)4 * 1024 * 1024);         // 4 MB
  float* stats = (float*)carve((size_t)13 * 256 * STP * 4);      // 208 KB
  float* zpage = (float*)carve(256);

  PackArgs pa;
  {
    size_t poff = 0;
    for (int L = 0; L < 13; ++L) {
      int ci = CIs[L], co = COs[L];
      int nkb = (27 * ci + 31) / 32;
      int ks = (nkb + 3) / 4;
      int nkbp = 4 * ks;  // padded for branch-free K-split
      pa.W[L] = (const float*)d_in[2 + 3 * L];
      pa.P[L] = Ppool + poff;
      pa.ci[L] = ci; pa.co[L] = co; pa.nkbp[L] = nkbp;
      poff += (size_t)nkbp * co * 32;
    }
  }

  const int n32 = GG * GG * GG / 2;
  k_clear_grid<<<2048, 256, 0, stream>>>((uint32_t*)grid, n32);
  k_scatter<<<(n + 255) / 256, 256, 0, stream>>>(coords, grid, n);
  k_rulebook<<<(n + 255) / 256, 256, 0, stream>>>(coords, grid, nidx, n);
  k_zero<<<208, 256, 0, stream>>>(stats, zpage);
  k_pack<<<dim3(128, 13), 256, 0, stream>>>(pa);

  // ---- layer 0 (f32 path, fused stats) ----
  k_sconv_l0<<<(n + 255) / 256, 256, 0, stream>>>(vf, pa.W[0], nidx, y, stats, n);
  k_bn_apply<16, false><<<((n * 16 / 8) + 255) / 256, 256, 0, stream>>>(
      y, stats, (const float*)d_in[3], (const float*)d_in[4], (void*)featA, n);

  // ---- layers 1..12 (MFMA path) ----
  short* cur = featA;
  short* nxt = featB;
  const int nblk = (n + 15) / 16;

#define RUN_MFMA(L, CI, CO, LAST)                                                             \
  do {                                                                                        \
    float* st = stats + 256 * STP * (L);                                                      \
    int zoff = (int)((char*)zpage - (char*)cur);                                              \
    k_sconv_mfma<CI, CO><<<nblk, 256, 0, stream>>>(cur, (const short*)pa.P[L], nidx,          \
                                                   zoff, y, n);                               \
    k_stats<CO><<<256, 256, 0, stream>>>(y, st, n);                                           \
    const float* gg = (const float*)d_in[3 + 3 * (L)];                                        \
    const float* bb = (const float*)d_in[4 + 3 * (L)];                                        \
    int nb = ((n * (CO) / 8) + 255) / 256;                                                    \
    if (LAST) {                                                                               \
      k_bn_apply<CO, true><<<nb, 256, 0, stream>>>(y, st, gg, bb, (void*)d_out, n);           \
    } else {                                                                                  \
      k_bn_apply<CO, false><<<nb, 256, 0, stream>>>(y, st, gg, bb, (void*)nxt, n);            \
      short* t_ = cur; cur = nxt; nxt = t_;                                                   \
    }                                                                                         \
  } while (0)

  RUN_MFMA(1, 16, 16, false);
  RUN_MFMA(2, 16, 32, false);
  RUN_MFMA(3, 32, 32, false);
  RUN_MFMA(4, 32, 32, false);
  RUN_MFMA(5, 32, 64, false);
  RUN_MFMA(6, 64, 64, false);
  RUN_MFMA(7, 64, 64, false);
  RUN_MFMA(8, 64, 64, false);
  RUN_MFMA(9, 64, 64, false);
  RUN_MFMA(10, 64, 64, false);
  RUN_MFMA(11, 64, 64, false);
  RUN_MFMA(12, 64, 128, true);
#undef RUN_MFMA
}